// Round 13
// baseline (1040.774 us; speedup 1.0000x reference)
//
#include <hip/hip_runtime.h>

#define D 128
#define NG 32
#define NC 10

typedef unsigned short ushort_t;
typedef __attribute__((ext_vector_type(8))) short short8v;
typedef __attribute__((ext_vector_type(4))) float float4v;
typedef __attribute__((ext_vector_type(2))) float float2v;

__device__ __forceinline__ ushort_t f2bf(float x) {
  union { float f; unsigned u; } v; v.f = x;
  unsigned r = (v.u + 0x7FFF + ((v.u >> 16) & 1)) >> 16;
  return (ushort_t)r;
}
__device__ __forceinline__ float bf2f(ushort_t b) {
  union { unsigned u; float f; } v; v.u = ((unsigned)b) << 16;
  return v.f;
}

// ---------------- degree + tickets: 2 atomics/edge (structural floor) ----------------
__global__ void degree_kernel(const int* __restrict__ src, const int* __restrict__ dst,
                              int* __restrict__ cout_, int* __restrict__ cursor,
                              int* __restrict__ rank, int E) {
  int i = blockIdx.x * 256 + threadIdx.x;
  int e0 = i * 4;
  if (e0 + 4 <= E) {
    int4 s = *(const int4*)(src + e0);
    int4 d_ = *(const int4*)(dst + e0);
    int r0 = atomicAdd(&cursor[d_.x], 1);
    int r1 = atomicAdd(&cursor[d_.y], 1);
    int r2 = atomicAdd(&cursor[d_.z], 1);
    int r3 = atomicAdd(&cursor[d_.w], 1);
    atomicAdd(&cout_[s.x], 1);
    atomicAdd(&cout_[s.y], 1);
    atomicAdd(&cout_[s.z], 1);
    atomicAdd(&cout_[s.w], 1);
    *(int4*)(rank + e0) = make_int4(r0, r1, r2, r3);
  } else {
    for (int e = e0; e < E; ++e) {
      rank[e] = atomicAdd(&cursor[dst[e]], 1);
      atomicAdd(&cout_[src[e]], 1);
    }
  }
}

// ---------------- scan ----------------
__global__ void scan1_kernel(const int* __restrict__ cnt, int* __restrict__ bsum, int n) {
  __shared__ int sdata[256];
  int base = blockIdx.x * 1024 + threadIdx.x * 4;
  int s = 0;
#pragma unroll
  for (int j = 0; j < 4; ++j) {
    int idx = base + j;
    if (idx < n) s += cnt[idx];
  }
  sdata[threadIdx.x] = s;
  __syncthreads();
  for (int off = 128; off > 0; off >>= 1) {
    if (threadIdx.x < off) sdata[threadIdx.x] += sdata[threadIdx.x + off];
    __syncthreads();
  }
  if (threadIdx.x == 0) bsum[blockIdx.x] = sdata[0];
}

__global__ void scan2_kernel(int* __restrict__ bsum, int nb) {
  __shared__ int s[1024];
  int t = threadIdx.x;
  int v = (t < nb) ? bsum[t] : 0;
  s[t] = v;
  __syncthreads();
  for (int off = 1; off < 1024; off <<= 1) {
    int add = (t >= off) ? s[t - off] : 0;
    __syncthreads();
    s[t] += add;
    __syncthreads();
  }
  if (t < nb) bsum[t] = s[t] - v;
}

__global__ void scan3_kernel(const int* __restrict__ cnt, const int* __restrict__ bsum,
                             int* __restrict__ rowptr, int n, int e_total) {
  __shared__ int ss[256];
  int t = threadIdx.x;
  int idx0 = blockIdx.x * 1024 + t * 4;
  int v[4]; int ts = 0;
#pragma unroll
  for (int j = 0; j < 4; ++j) {
    v[j] = (idx0 + j < n) ? cnt[idx0 + j] : 0;
    ts += v[j];
  }
  ss[t] = ts;
  __syncthreads();
  for (int off = 1; off < 256; off <<= 1) {
    int add = 0;
    if (t >= off) add = ss[t - off];
    __syncthreads();
    if (t >= off) ss[t] += add;
    __syncthreads();
  }
  int excl = ss[t] - ts + bsum[blockIdx.x];
#pragma unroll
  for (int j = 0; j < 4; ++j) {
    int idx = idx0 + j;
    if (idx < n) rowptr[idx] = excl;
    excl += v[j];
  }
  if (blockIdx.x == 0 && t == 0) rowptr[n] = e_total;
}

// ---------------- pass B: atomic-free scatter ----------------
__global__ void passB_kernel(const int* __restrict__ src, const int* __restrict__ dst,
                             const int* __restrict__ rank, const int* __restrict__ rowptr,
                             int* __restrict__ csrc, int E) {
  int i = blockIdx.x * 256 + threadIdx.x;
  int e0 = i * 4;
  if (e0 + 4 <= E) {
    int4 s = *(const int4*)(src + e0);
    int4 d_ = *(const int4*)(dst + e0);
    int4 r = *(const int4*)(rank + e0);
    csrc[rowptr[d_.x] + r.x] = s.x;
    csrc[rowptr[d_.y] + r.y] = s.y;
    csrc[rowptr[d_.z] + r.z] = s.z;
    csrc[rowptr[d_.w] + r.w] = s.w;
  } else {
    for (int e = e0; e < E; ++e)
      csrc[rowptr[dst[e]] + rank[e]] = src[e];
  }
}

// ---------------- conversions ----------------
__global__ void cvt_h_kernel(const float* __restrict__ h, ushort_t* __restrict__ hb, long total) {
  long i4 = ((long)blockIdx.x * 256 + threadIdx.x) * 4;
  if (i4 + 4 <= total) {
    float4 v = *(const float4*)(h + i4);
    ushort_t o[4] = { f2bf(v.x), f2bf(v.y), f2bf(v.z), f2bf(v.w) };
    *(uint2*)(hb + i4) = *(const uint2*)o;
  } else {
    for (long i = i4; i < total; ++i) hb[i] = f2bf(h[i]);
  }
}

__global__ void cvt_w_kernel(const float* __restrict__ W1, const float* __restrict__ W2,
                             const float* __restrict__ W3, const float* __restrict__ W4,
                             ushort_t* __restrict__ Wt) {
  const float* Ws[4] = { W1, W2, W3, W4 };
  const float* W = Ws[blockIdx.x];
  ushort_t* o = Wt + (size_t)blockIdx.x * D * D;
  for (int idx = threadIdx.x; idx < D * D; idx += 256) {
    int c = idx >> 7, k = idx & 127;
    o[c * D + k] = f2bf(W[k * D + c]);
  }
}

// ---------------- MFMA GEMM: X[n,128] = fp8( iout * (A @ W) ), A bf16, Wt = W^T bf16 ----------------
__global__ __launch_bounds__(256) void gemm_mfma_kernel(const ushort_t* __restrict__ A,
    const ushort_t* __restrict__ Wt, const int* __restrict__ cout_,
    unsigned char* __restrict__ X, int n) {
  int wave = threadIdx.x >> 6;
  int lane = threadIdx.x & 63;
  int g = lane >> 4;
  int lr = lane & 15;
  int rowbase = blockIdx.x * 64 + wave * 16;
  int arow = rowbase + lr;
  int arow_c = arow < n ? arow : (n - 1);
  const ushort_t* Ap = A + (size_t)arow_c * D + g * 8;

  short8v afrag[4];
#pragma unroll
  for (int ks = 0; ks < 4; ++ks)
    afrag[ks] = *(const short8v*)(Ap + ks * 32);

  float4v acc[8];
#pragma unroll
  for (int ct = 0; ct < 8; ++ct)
#pragma unroll
    for (int r = 0; r < 4; ++r) acc[ct][r] = 0.f;

#pragma unroll
  for (int ct = 0; ct < 8; ++ct) {
    const ushort_t* bp = Wt + (size_t)(ct * 16 + lr) * D + g * 8;
#pragma unroll
    for (int ks = 0; ks < 4; ++ks) {
      short8v bfrag = *(const short8v*)(bp + ks * 32);
      acc[ct] = __builtin_amdgcn_mfma_f32_16x16x32_bf16(afrag[ks], bfrag, acc[ct], 0, 0, 0);
    }
  }

  float scv[4];
  bool rok[4];
#pragma unroll
  for (int r = 0; r < 4; ++r) {
    int grow = rowbase + g * 4 + r;
    rok[r] = grow < n;
    int gc = rok[r] ? grow : (n - 1);
    scv[r] = rsqrtf(fmaxf((float)cout_[gc], 1.f));
  }
#pragma unroll
  for (int ct = 0; ct < 8; ++ct) {
#pragma unroll
    for (int r = 0; r < 4; ++r) {
      int grow = rowbase + g * 4 + r;
      if (rok[r]) {
        int p = __builtin_amdgcn_cvt_pk_fp8_f32(acc[ct][r] * scv[r], 0.f, 0, false);
        X[(size_t)grow * D + ct * 16 + lr] = (unsigned char)(p & 0xff);
      }
    }
  }
}

// ---------------- aggregation: 8 slots x 8 lanes x 16 fp8 (uint4 loads, 8 rows/wave-instr) ----------------
#define ACC16(u)                                                                   \
  { float2v f;                                                                     \
    f = __builtin_amdgcn_cvt_pk_f32_fp8((u).x, false); acc[0] += f[0];  acc[1] += f[1];  \
    f = __builtin_amdgcn_cvt_pk_f32_fp8((u).x, true);  acc[2] += f[0];  acc[3] += f[1];  \
    f = __builtin_amdgcn_cvt_pk_f32_fp8((u).y, false); acc[4] += f[0];  acc[5] += f[1];  \
    f = __builtin_amdgcn_cvt_pk_f32_fp8((u).y, true);  acc[6] += f[0];  acc[7] += f[1];  \
    f = __builtin_amdgcn_cvt_pk_f32_fp8((u).z, false); acc[8] += f[0];  acc[9] += f[1];  \
    f = __builtin_amdgcn_cvt_pk_f32_fp8((u).z, true);  acc[10] += f[0]; acc[11] += f[1]; \
    f = __builtin_amdgcn_cvt_pk_f32_fp8((u).w, false); acc[12] += f[0]; acc[13] += f[1]; \
    f = __builtin_amdgcn_cvt_pk_f32_fp8((u).w, true);  acc[14] += f[0]; acc[15] += f[1]; }

__global__ __launch_bounds__(256) void agg_relu_kernel(const unsigned char* __restrict__ x,
    const int* __restrict__ rowptr, const int* __restrict__ csrc,
    const int* __restrict__ cin_, const float* __restrict__ bias,
    ushort_t* __restrict__ y, int n) {
  int node = blockIdx.x * 4 + (threadIdx.x >> 6);
  if (node >= n) return;
  int lane = threadIdx.x & 63;
  int slot = lane >> 3;       // edge slot 0..7
  int lr = lane & 7;          // 16 cols per lane: [lr*16, lr*16+16)
  int beg = rowptr[node], end = rowptr[node + 1];
  float acc[16];
#pragma unroll
  for (int j = 0; j < 16; ++j) acc[j] = 0.f;

  const unsigned char* xp = x + lr * 16;
  int e = beg;

  // alignment prologue: bring e to multiple of 4 (slots 0..2 cover <=3 edges)
  int pro = (beg + 3) & ~3;
  if (pro > beg) {
    int ee = beg + slot;
    if (ee < end && ee < pro) {
      int s = csrc[ee];
      uint4 u = *(const uint4*)(xp + (size_t)s * D);
      ACC16(u);
    }
    e = pro < end ? pro : end;
  }
  // 32-edge main loop: slot takes contiguous edges e+4*slot.. via one int4 load; 8 rows in flight
  for (; e + 32 <= end; e += 32) {
    int4 s4 = *(const int4*)(csrc + e + slot * 4);
    uint4 u0 = *(const uint4*)(xp + (size_t)s4.x * D);
    uint4 u1 = *(const uint4*)(xp + (size_t)s4.y * D);
    uint4 u2 = *(const uint4*)(xp + (size_t)s4.z * D);
    uint4 u3 = *(const uint4*)(xp + (size_t)s4.w * D);
    ACC16(u0); ACC16(u1); ACC16(u2); ACC16(u3);
  }
  // 8-edge steps (1 edge per slot)
  for (; e + 8 <= end; e += 8) {
    int s = csrc[e + slot];
    uint4 u = *(const uint4*)(xp + (size_t)s * D);
    ACC16(u);
  }
  // tail (<8)
  if (e + slot < end) {
    int s = csrc[e + slot];
    uint4 u = *(const uint4*)(xp + (size_t)s * D);
    ACC16(u);
  }

#pragma unroll
  for (int j = 0; j < 16; ++j) {
    acc[j] += __shfl_xor(acc[j], 8, 64);
    acc[j] += __shfl_xor(acc[j], 16, 64);
    acc[j] += __shfl_xor(acc[j], 32, 64);
  }
  if (slot == 0) {
    float wi = rsqrtf(fmaxf((float)cin_[node], 1.f));
    ushort_t o[16];
#pragma unroll
    for (int j4 = 0; j4 < 4; ++j4) {
      float4 bb = *(const float4*)(bias + lr * 16 + j4 * 4);
      o[j4 * 4 + 0] = f2bf(fmaxf(acc[j4 * 4 + 0] * wi + bb.x, 0.f));
      o[j4 * 4 + 1] = f2bf(fmaxf(acc[j4 * 4 + 1] * wi + bb.y, 0.f));
      o[j4 * 4 + 2] = f2bf(fmaxf(acc[j4 * 4 + 2] * wi + bb.z, 0.f));
      o[j4 * 4 + 3] = f2bf(fmaxf(acc[j4 * 4 + 3] * wi + bb.w, 0.f));
    }
    *(uint4*)(y + (size_t)node * D + lr * 16) = *(const uint4*)o;
    *(uint4*)(y + (size_t)node * D + lr * 16 + 8) = *(const uint4*)(o + 8);
  }
}

// ---------------- pooling (bf16 in) ----------------
__device__ int lower_bound_gid(const int* gid, int n, int g) {
  int lo = 0, hi = n;
  while (lo < hi) { int mid = (lo + hi) >> 1; if (gid[mid] < g) lo = mid + 1; else hi = mid; }
  return lo;
}

__global__ void pool_kernel(const ushort_t* __restrict__ x, const int* __restrict__ gid,
                            float* __restrict__ sums, int* __restrict__ counts, int n) {
  int g = blockIdx.x >> 3, part = blockIdx.x & 7;
  __shared__ int s_lo, s_hi;
  if (threadIdx.x == 0) {
    s_lo = lower_bound_gid(gid, n, g);
    s_hi = lower_bound_gid(gid, n, g + 1);
    if (part == 0) counts[g] = s_hi - s_lo;
  }
  __syncthreads();
  int lo = s_lo, hi = s_hi;
  int cnt = hi - lo;
  int per = (cnt + 7) >> 3;
  int a = lo + part * per;
  int bnd = min(a + per, hi);
  int t = threadIdx.x;
  float acc = 0.f;
  for (int i = a; i < bnd; ++i) acc += bf2f(x[(size_t)i * D + t]);
  atomicAdd(&sums[g * D + t], acc);
}

// ---------------- classifier ----------------
__global__ __launch_bounds__(128) void classifier_kernel(const float* __restrict__ sums,
    const int* __restrict__ counts, const float* __restrict__ Wc1, const float* __restrict__ bc1,
    const float* __restrict__ Wc2, const float* __restrict__ bc2, float* __restrict__ out) {
  __shared__ float hg[NG][D];
  __shared__ float hid[NG][D];
  int t = threadIdx.x;
#pragma unroll
  for (int g = 0; g < NG; ++g)
    hg[g][t] = sums[g * D + t] / fmaxf((float)counts[g], 1.f);
  __syncthreads();
  float acc[NG];
#pragma unroll
  for (int g = 0; g < NG; ++g) acc[g] = bc1[t];
  for (int k = 0; k < D; ++k) {
    float w = Wc1[k * D + t];
#pragma unroll
    for (int g = 0; g < NG; ++g) acc[g] += hg[g][k] * w;
  }
#pragma unroll
  for (int g = 0; g < NG; ++g) hid[g][t] = fmaxf(acc[g], 0.f);
  __syncthreads();
  for (int idx = t; idx < NG * NC; idx += 128) {
    int g = idx / NC, c = idx % NC;
    float a = bc2[c];
    for (int j = 0; j < D; ++j) a += hid[g][j] * Wc2[j * NC + c];
    out[idx] = a;
  }
}

extern "C" void kernel_launch(void* const* d_in, const int* in_sizes, int n_in,
                              void* d_out, int out_size, void* d_ws, size_t ws_size,
                              hipStream_t stream) {
  const float* h   = (const float*)d_in[0];
  const int* src   = (const int*)d_in[1];
  const int* dst   = (const int*)d_in[2];
  const int* gid   = (const int*)d_in[3];
  const float* W1  = (const float*)d_in[4];
  const float* b1  = (const float*)d_in[5];
  const float* W2  = (const float*)d_in[6];
  const float* b2  = (const float*)d_in[7];
  const float* W3  = (const float*)d_in[8];
  const float* b3  = (const float*)d_in[9];
  const float* W4  = (const float*)d_in[10];
  const float* b4  = (const float*)d_in[11];
  const float* Wc1 = (const float*)d_in[12];
  const float* bc1 = (const float*)d_in[13];
  const float* Wc2 = (const float*)d_in[14];
  const float* bc2 = (const float*)d_in[15];
  float* out = (float*)d_out;

  const int N = in_sizes[3];
  const int E = in_sizes[1];

  char* ws = (char*)d_ws;
  size_t off = 0;
  auto alloc = [&](size_t bytes) -> char* {
    char* p = ws + off;
    off = (off + bytes + 255) & ~(size_t)255;
    return p;
  };

  int* cnts     = (int*)alloc((size_t)2 * N * 4);   // cout | cursor(->in-degree)
  int* cout_    = cnts;
  int* cursor   = cnts + N;
  int* rowptr   = (int*)alloc((size_t)(N + 1) * 4);
  int* bsum     = (int*)alloc(4096);
  int* csrc     = (int*)alloc((size_t)E * 4);
  ushort_t* Wt  = (ushort_t*)alloc((size_t)4 * D * D * 2);
  unsigned char* Xb = (unsigned char*)alloc((size_t)N * D);  // fp8 pre-agg (iout-scaled)
  ushort_t* Yb  = (ushort_t*)alloc((size_t)N * D * 2);       // bf16 agg out; head: rank[] then Hb
  float* sums   = (float*)alloc((size_t)(NG * D + NG) * 4);
  int* counts   = (int*)(sums + NG * D);
  int* rank     = (int*)Yb;        // overlay 1: consumed by passB
  ushort_t* Hb  = Yb;              // overlay 2: bf16(h), written after passB, dead after gemm1

  hipMemsetAsync(cnts, 0, (size_t)2 * N * 4, stream);
  hipMemsetAsync(sums, 0, (size_t)(NG * D + NG) * 4, stream);

  int gE4 = (E / 4 + 255) / 256 + 1;
  int nb  = (N + 1023) / 1024;
  int gAgg  = (N + 3) / 4;
  int gGemm = (N + 63) / 64;
  long totalH = (long)N * D;
  int gCvt = (int)((totalH / 4 + 255) / 256) + 1;

  degree_kernel<<<gE4, 256, 0, stream>>>(src, dst, cout_, cursor, rank, E);
  scan1_kernel<<<nb, 256, 0, stream>>>(cursor, bsum, N);
  scan2_kernel<<<1, 1024, 0, stream>>>(bsum, nb);
  scan3_kernel<<<nb, 256, 0, stream>>>(cursor, bsum, rowptr, N, E);
  passB_kernel<<<gE4, 256, 0, stream>>>(src, dst, rank, rowptr, csrc, E);

  cvt_w_kernel<<<4, 256, 0, stream>>>(W1, W2, W3, W4, Wt);
  cvt_h_kernel<<<gCvt, 256, 0, stream>>>(h, Hb, totalH);

  // layer 1
  gemm_mfma_kernel<<<gGemm, 256, 0, stream>>>(Hb, Wt, cout_, Xb, N);
  agg_relu_kernel<<<gAgg, 256, 0, stream>>>(Xb, rowptr, csrc, cursor, b1, Yb, N);
  // layer 2
  gemm_mfma_kernel<<<gGemm, 256, 0, stream>>>(Yb, Wt + (size_t)1 * D * D, cout_, Xb, N);
  agg_relu_kernel<<<gAgg, 256, 0, stream>>>(Xb, rowptr, csrc, cursor, b2, Yb, N);
  // layer 3
  gemm_mfma_kernel<<<gGemm, 256, 0, stream>>>(Yb, Wt + (size_t)2 * D * D, cout_, Xb, N);
  agg_relu_kernel<<<gAgg, 256, 0, stream>>>(Xb, rowptr, csrc, cursor, b3, Yb, N);
  // layer 4
  gemm_mfma_kernel<<<gGemm, 256, 0, stream>>>(Yb, Wt + (size_t)3 * D * D, cout_, Xb, N);
  agg_relu_kernel<<<gAgg, 256, 0, stream>>>(Xb, rowptr, csrc, cursor, b4, Yb, N);

  pool_kernel<<<NG * 8, 128, 0, stream>>>(Yb, gid, sums, counts, N);
  classifier_kernel<<<1, 128, 0, stream>>>(sums, counts, Wc1, bc1, Wc2, bc2, out);
}

// Round 14
// 907.479 us; speedup vs baseline: 1.1469x; 1.1469x over previous
//
#include <hip/hip_runtime.h>

#define D 128
#define NG 32
#define NC 10

typedef unsigned short ushort_t;
typedef __attribute__((ext_vector_type(8))) short short8v;
typedef __attribute__((ext_vector_type(4))) float float4v;
typedef __attribute__((ext_vector_type(2))) float float2v;

__device__ __forceinline__ ushort_t f2bf(float x) {
  union { float f; unsigned u; } v; v.f = x;
  unsigned r = (v.u + 0x7FFF + ((v.u >> 16) & 1)) >> 16;
  return (ushort_t)r;
}
__device__ __forceinline__ float bf2f(ushort_t b) {
  union { unsigned u; float f; } v; v.u = ((unsigned)b) << 16;
  return v.f;
}

// ---------------- degree + tickets: 2 atomics/edge (structural floor) ----------------
__global__ void degree_kernel(const int* __restrict__ src, const int* __restrict__ dst,
                              int* __restrict__ cout_, int* __restrict__ cursor,
                              int* __restrict__ rank, int E) {
  int i = blockIdx.x * 256 + threadIdx.x;
  int e0 = i * 4;
  if (e0 + 4 <= E) {
    int4 s = *(const int4*)(src + e0);
    int4 d_ = *(const int4*)(dst + e0);
    int r0 = atomicAdd(&cursor[d_.x], 1);
    int r1 = atomicAdd(&cursor[d_.y], 1);
    int r2 = atomicAdd(&cursor[d_.z], 1);
    int r3 = atomicAdd(&cursor[d_.w], 1);
    atomicAdd(&cout_[s.x], 1);
    atomicAdd(&cout_[s.y], 1);
    atomicAdd(&cout_[s.z], 1);
    atomicAdd(&cout_[s.w], 1);
    *(int4*)(rank + e0) = make_int4(r0, r1, r2, r3);
  } else {
    for (int e = e0; e < E; ++e) {
      rank[e] = atomicAdd(&cursor[dst[e]], 1);
      atomicAdd(&cout_[src[e]], 1);
    }
  }
}

// ---------------- scan ----------------
__global__ void scan1_kernel(const int* __restrict__ cnt, int* __restrict__ bsum, int n) {
  __shared__ int sdata[256];
  int base = blockIdx.x * 1024 + threadIdx.x * 4;
  int s = 0;
#pragma unroll
  for (int j = 0; j < 4; ++j) {
    int idx = base + j;
    if (idx < n) s += cnt[idx];
  }
  sdata[threadIdx.x] = s;
  __syncthreads();
  for (int off = 128; off > 0; off >>= 1) {
    if (threadIdx.x < off) sdata[threadIdx.x] += sdata[threadIdx.x + off];
    __syncthreads();
  }
  if (threadIdx.x == 0) bsum[blockIdx.x] = sdata[0];
}

// parallel exclusive scan of block sums (nb <= 1024)
__global__ void scan2_kernel(int* __restrict__ bsum, int nb) {
  __shared__ int s[1024];
  int t = threadIdx.x;
  int v = (t < nb) ? bsum[t] : 0;
  s[t] = v;
  __syncthreads();
  for (int off = 1; off < 1024; off <<= 1) {
    int add = (t >= off) ? s[t - off] : 0;
    __syncthreads();
    s[t] += add;
    __syncthreads();
  }
  if (t < nb) bsum[t] = s[t] - v;
}

__global__ void scan3_kernel(const int* __restrict__ cnt, const int* __restrict__ bsum,
                             int* __restrict__ rowptr, int n, int e_total) {
  __shared__ int ss[256];
  int t = threadIdx.x;
  int idx0 = blockIdx.x * 1024 + t * 4;
  int v[4]; int ts = 0;
#pragma unroll
  for (int j = 0; j < 4; ++j) {
    v[j] = (idx0 + j < n) ? cnt[idx0 + j] : 0;
    ts += v[j];
  }
  ss[t] = ts;
  __syncthreads();
  for (int off = 1; off < 256; off <<= 1) {
    int add = 0;
    if (t >= off) add = ss[t - off];
    __syncthreads();
    if (t >= off) ss[t] += add;
    __syncthreads();
  }
  int excl = ss[t] - ts + bsum[blockIdx.x];
#pragma unroll
  for (int j = 0; j < 4; ++j) {
    int idx = idx0 + j;
    if (idx < n) rowptr[idx] = excl;
    excl += v[j];
  }
  if (blockIdx.x == 0 && t == 0) rowptr[n] = e_total;
}

// ---------------- pass B: atomic-free scatter ----------------
__global__ void passB_kernel(const int* __restrict__ src, const int* __restrict__ dst,
                             const int* __restrict__ rank, const int* __restrict__ rowptr,
                             int* __restrict__ csrc, int E) {
  int i = blockIdx.x * 256 + threadIdx.x;
  int e0 = i * 4;
  if (e0 + 4 <= E) {
    int4 s = *(const int4*)(src + e0);
    int4 d_ = *(const int4*)(dst + e0);
    int4 r = *(const int4*)(rank + e0);
    csrc[rowptr[d_.x] + r.x] = s.x;
    csrc[rowptr[d_.y] + r.y] = s.y;
    csrc[rowptr[d_.z] + r.z] = s.z;
    csrc[rowptr[d_.w] + r.w] = s.w;
  } else {
    for (int e = e0; e < E; ++e)
      csrc[rowptr[dst[e]] + rank[e]] = src[e];
  }
}

// ---------------- conversions ----------------
__global__ void cvt_h_kernel(const float* __restrict__ h, ushort_t* __restrict__ hb, long total) {
  long i4 = ((long)blockIdx.x * 256 + threadIdx.x) * 4;
  if (i4 + 4 <= total) {
    float4 v = *(const float4*)(h + i4);
    ushort_t o[4] = { f2bf(v.x), f2bf(v.y), f2bf(v.z), f2bf(v.w) };
    *(uint2*)(hb + i4) = *(const uint2*)o;
  } else {
    for (long i = i4; i < total; ++i) hb[i] = f2bf(h[i]);
  }
}

__global__ void cvt_w_kernel(const float* __restrict__ W1, const float* __restrict__ W2,
                             const float* __restrict__ W3, const float* __restrict__ W4,
                             ushort_t* __restrict__ Wt) {
  const float* Ws[4] = { W1, W2, W3, W4 };
  const float* W = Ws[blockIdx.x];
  ushort_t* o = Wt + (size_t)blockIdx.x * D * D;
  for (int idx = threadIdx.x; idx < D * D; idx += 256) {
    int c = idx >> 7, k = idx & 127;
    o[c * D + k] = f2bf(W[k * D + c]);
  }
}

// ---------------- MFMA GEMM: X[n,128] = fp8( iout * (A @ W) ), A bf16, Wt = W^T bf16 ----------------
__global__ __launch_bounds__(256) void gemm_mfma_kernel(const ushort_t* __restrict__ A,
    const ushort_t* __restrict__ Wt, const int* __restrict__ cout_,
    unsigned char* __restrict__ X, int n) {
  int wave = threadIdx.x >> 6;
  int lane = threadIdx.x & 63;
  int g = lane >> 4;
  int lr = lane & 15;
  int rowbase = blockIdx.x * 64 + wave * 16;
  int arow = rowbase + lr;
  int arow_c = arow < n ? arow : (n - 1);
  const ushort_t* Ap = A + (size_t)arow_c * D + g * 8;

  short8v afrag[4];
#pragma unroll
  for (int ks = 0; ks < 4; ++ks)
    afrag[ks] = *(const short8v*)(Ap + ks * 32);

  float4v acc[8];
#pragma unroll
  for (int ct = 0; ct < 8; ++ct)
#pragma unroll
    for (int r = 0; r < 4; ++r) acc[ct][r] = 0.f;

#pragma unroll
  for (int ct = 0; ct < 8; ++ct) {
    const ushort_t* bp = Wt + (size_t)(ct * 16 + lr) * D + g * 8;
#pragma unroll
    for (int ks = 0; ks < 4; ++ks) {
      short8v bfrag = *(const short8v*)(bp + ks * 32);
      acc[ct] = __builtin_amdgcn_mfma_f32_16x16x32_bf16(afrag[ks], bfrag, acc[ct], 0, 0, 0);
    }
  }

  float scv[4];
  bool rok[4];
#pragma unroll
  for (int r = 0; r < 4; ++r) {
    int grow = rowbase + g * 4 + r;
    rok[r] = grow < n;
    int gc = rok[r] ? grow : (n - 1);
    scv[r] = rsqrtf(fmaxf((float)cout_[gc], 1.f));
  }
#pragma unroll
  for (int ct = 0; ct < 8; ++ct) {
#pragma unroll
    for (int r = 0; r < 4; ++r) {
      int grow = rowbase + g * 4 + r;
      if (rok[r]) {
        int p = __builtin_amdgcn_cvt_pk_fp8_f32(acc[ct][r] * scv[r], 0.f, 0, false);
        X[(size_t)grow * D + ct * 16 + lr] = (unsigned char)(p & 0xff);
      }
    }
  }
}

// ---------------- aggregation: quarter-wave, 16-edge main loop (4 gathers in flight/lane) ----------------
#define ACC8(u)                                                                  \
  { float2v f;                                                                   \
    f = __builtin_amdgcn_cvt_pk_f32_fp8((u).x, false); acc[0] += f[0]; acc[1] += f[1]; \
    f = __builtin_amdgcn_cvt_pk_f32_fp8((u).x, true);  acc[2] += f[0]; acc[3] += f[1]; \
    f = __builtin_amdgcn_cvt_pk_f32_fp8((u).y, false); acc[4] += f[0]; acc[5] += f[1]; \
    f = __builtin_amdgcn_cvt_pk_f32_fp8((u).y, true);  acc[6] += f[0]; acc[7] += f[1]; }

__global__ __launch_bounds__(256) void agg_relu_kernel(const unsigned char* __restrict__ x,
    const int* __restrict__ rowptr, const int* __restrict__ csrc,
    const int* __restrict__ cin_, const float* __restrict__ bias,
    ushort_t* __restrict__ y, int n) {
  int node = blockIdx.x * 4 + (threadIdx.x >> 6);
  if (node >= n) return;
  int lane = threadIdx.x & 63;
  int q = lane >> 4;          // quarter 0..3
  int lr = lane & 15;         // 8 cols per lane
  int beg = rowptr[node], end = rowptr[node + 1];
  float acc[8];
#pragma unroll
  for (int j = 0; j < 8; ++j) acc[j] = 0.f;

  const unsigned char* xp = x + lr * 8;
  int e = beg;

  // alignment prologue: bring e to a multiple of 4 (for int4 csrc loads)
  int aligned = (beg + 3) & ~3;
  if (aligned > beg) {
    int ee = beg + q;
    if (ee < end && ee < aligned) {
      int s = csrc[ee];
      uint2 u = *(const uint2*)(xp + (size_t)s * D);
      ACC8(u);
    }
    e = aligned < end ? aligned : end;
  }
  // 16-edge main loop: quarter q takes contiguous edges e+4q..e+4q+3 via one int4 load
  for (; e + 16 <= end; e += 16) {
    int4 s4 = *(const int4*)(csrc + e + q * 4);
    uint2 u0 = *(const uint2*)(xp + (size_t)s4.x * D);
    uint2 u1 = *(const uint2*)(xp + (size_t)s4.y * D);
    uint2 u2 = *(const uint2*)(xp + (size_t)s4.z * D);
    uint2 u3 = *(const uint2*)(xp + (size_t)s4.w * D);
    ACC8(u0); ACC8(u1); ACC8(u2); ACC8(u3);
  }
  // 8-edge step
  if (e + 8 <= end) {
    int s0 = csrc[e + q];
    int s1 = csrc[e + 4 + q];
    uint2 u0 = *(const uint2*)(xp + (size_t)s0 * D);
    uint2 u1 = *(const uint2*)(xp + (size_t)s1 * D);
    ACC8(u0); ACC8(u1);
    e += 8;
  }
  // 4-edge step
  if (e + 4 <= end) {
    int s = csrc[e + q];
    uint2 u = *(const uint2*)(xp + (size_t)s * D);
    ACC8(u);
    e += 4;
  }
  // tail (<4)
  {
    int ee = e + q;
    if (ee < end) {
      int s = csrc[ee];
      uint2 u = *(const uint2*)(xp + (size_t)s * D);
      ACC8(u);
    }
  }

#pragma unroll
  for (int j = 0; j < 8; ++j) {
    acc[j] += __shfl_xor(acc[j], 16, 64);
    acc[j] += __shfl_xor(acc[j], 32, 64);
  }
  if (q == 0) {
    float wi = rsqrtf(fmaxf((float)cin_[node], 1.f));
    float4 b0 = *(const float4*)(bias + lr * 8);
    float4 b1 = *(const float4*)(bias + lr * 8 + 4);
    ushort_t o[8];
    o[0] = f2bf(fmaxf(acc[0] * wi + b0.x, 0.f));
    o[1] = f2bf(fmaxf(acc[1] * wi + b0.y, 0.f));
    o[2] = f2bf(fmaxf(acc[2] * wi + b0.z, 0.f));
    o[3] = f2bf(fmaxf(acc[3] * wi + b0.w, 0.f));
    o[4] = f2bf(fmaxf(acc[4] * wi + b1.x, 0.f));
    o[5] = f2bf(fmaxf(acc[5] * wi + b1.y, 0.f));
    o[6] = f2bf(fmaxf(acc[6] * wi + b1.z, 0.f));
    o[7] = f2bf(fmaxf(acc[7] * wi + b1.w, 0.f));
    *(uint4*)(y + (size_t)node * D + lr * 8) = *(const uint4*)o;
  }
}

// ---------------- pooling (bf16 in) ----------------
__device__ int lower_bound_gid(const int* gid, int n, int g) {
  int lo = 0, hi = n;
  while (lo < hi) { int mid = (lo + hi) >> 1; if (gid[mid] < g) lo = mid + 1; else hi = mid; }
  return lo;
}

__global__ void pool_kernel(const ushort_t* __restrict__ x, const int* __restrict__ gid,
                            float* __restrict__ sums, int* __restrict__ counts, int n) {
  int g = blockIdx.x >> 3, part = blockIdx.x & 7;
  __shared__ int s_lo, s_hi;
  if (threadIdx.x == 0) {
    s_lo = lower_bound_gid(gid, n, g);
    s_hi = lower_bound_gid(gid, n, g + 1);
    if (part == 0) counts[g] = s_hi - s_lo;
  }
  __syncthreads();
  int lo = s_lo, hi = s_hi;
  int cnt = hi - lo;
  int per = (cnt + 7) >> 3;
  int a = lo + part * per;
  int bnd = min(a + per, hi);
  int t = threadIdx.x;
  float acc = 0.f;
  for (int i = a; i < bnd; ++i) acc += bf2f(x[(size_t)i * D + t]);
  atomicAdd(&sums[g * D + t], acc);
}

// ---------------- classifier ----------------
__global__ __launch_bounds__(128) void classifier_kernel(const float* __restrict__ sums,
    const int* __restrict__ counts, const float* __restrict__ Wc1, const float* __restrict__ bc1,
    const float* __restrict__ Wc2, const float* __restrict__ bc2, float* __restrict__ out) {
  __shared__ float hg[NG][D];
  __shared__ float hid[NG][D];
  int t = threadIdx.x;
#pragma unroll
  for (int g = 0; g < NG; ++g)
    hg[g][t] = sums[g * D + t] / fmaxf((float)counts[g], 1.f);
  __syncthreads();
  float acc[NG];
#pragma unroll
  for (int g = 0; g < NG; ++g) acc[g] = bc1[t];
  for (int k = 0; k < D; ++k) {
    float w = Wc1[k * D + t];
#pragma unroll
    for (int g = 0; g < NG; ++g) acc[g] += hg[g][k] * w;
  }
#pragma unroll
  for (int g = 0; g < NG; ++g) hid[g][t] = fmaxf(acc[g], 0.f);
  __syncthreads();
  for (int idx = t; idx < NG * NC; idx += 128) {
    int g = idx / NC, c = idx % NC;
    float a = bc2[c];
    for (int j = 0; j < D; ++j) a += hid[g][j] * Wc2[j * NC + c];
    out[idx] = a;
  }
}

extern "C" void kernel_launch(void* const* d_in, const int* in_sizes, int n_in,
                              void* d_out, int out_size, void* d_ws, size_t ws_size,
                              hipStream_t stream) {
  const float* h   = (const float*)d_in[0];
  const int* src   = (const int*)d_in[1];
  const int* dst   = (const int*)d_in[2];
  const int* gid   = (const int*)d_in[3];
  const float* W1  = (const float*)d_in[4];
  const float* b1  = (const float*)d_in[5];
  const float* W2  = (const float*)d_in[6];
  const float* b2  = (const float*)d_in[7];
  const float* W3  = (const float*)d_in[8];
  const float* b3  = (const float*)d_in[9];
  const float* W4  = (const float*)d_in[10];
  const float* b4  = (const float*)d_in[11];
  const float* Wc1 = (const float*)d_in[12];
  const float* bc1 = (const float*)d_in[13];
  const float* Wc2 = (const float*)d_in[14];
  const float* bc2 = (const float*)d_in[15];
  float* out = (float*)d_out;

  const int N = in_sizes[3];
  const int E = in_sizes[1];

  char* ws = (char*)d_ws;
  size_t off = 0;
  auto alloc = [&](size_t bytes) -> char* {
    char* p = ws + off;
    off = (off + bytes + 255) & ~(size_t)255;
    return p;
  };

  int* cnts     = (int*)alloc((size_t)2 * N * 4);   // cout | cursor(->in-degree)
  int* cout_    = cnts;
  int* cursor   = cnts + N;
  int* rowptr   = (int*)alloc((size_t)(N + 1) * 4);
  int* bsum     = (int*)alloc(4096);
  int* csrc     = (int*)alloc((size_t)E * 4);
  ushort_t* Wt  = (ushort_t*)alloc((size_t)4 * D * D * 2);
  unsigned char* Xb = (unsigned char*)alloc((size_t)N * D);  // fp8 pre-agg (iout-scaled)
  ushort_t* Yb  = (ushort_t*)alloc((size_t)N * D * 2);       // bf16 agg out; head: rank[] then Hb
  float* sums   = (float*)alloc((size_t)(NG * D + NG) * 4);
  int* counts   = (int*)(sums + NG * D);
  int* rank     = (int*)Yb;        // overlay 1: consumed by passB
  ushort_t* Hb  = Yb;              // overlay 2: bf16(h), written after passB, dead after gemm1

  hipMemsetAsync(cnts, 0, (size_t)2 * N * 4, stream);
  hipMemsetAsync(sums, 0, (size_t)(NG * D + NG) * 4, stream);

  int gE4 = (E / 4 + 255) / 256 + 1;
  int nb  = (N + 1023) / 1024;
  int gAgg  = (N + 3) / 4;
  int gGemm = (N + 63) / 64;
  long totalH = (long)N * D;
  int gCvt = (int)((totalH / 4 + 255) / 256) + 1;

  degree_kernel<<<gE4, 256, 0, stream>>>(src, dst, cout_, cursor, rank, E);
  scan1_kernel<<<nb, 256, 0, stream>>>(cursor, bsum, N);
  scan2_kernel<<<1, 1024, 0, stream>>>(bsum, nb);
  scan3_kernel<<<nb, 256, 0, stream>>>(cursor, bsum, rowptr, N, E);
  passB_kernel<<<gE4, 256, 0, stream>>>(src, dst, rank, rowptr, csrc, E);

  cvt_w_kernel<<<4, 256, 0, stream>>>(W1, W2, W3, W4, Wt);
  cvt_h_kernel<<<gCvt, 256, 0, stream>>>(h, Hb, totalH);

  // layer 1
  gemm_mfma_kernel<<<gGemm, 256, 0, stream>>>(Hb, Wt, cout_, Xb, N);
  agg_relu_kernel<<<gAgg, 256, 0, stream>>>(Xb, rowptr, csrc, cursor, b1, Yb, N);
  // layer 2
  gemm_mfma_kernel<<<gGemm, 256, 0, stream>>>(Yb, Wt + (size_t)1 * D * D, cout_, Xb, N);
  agg_relu_kernel<<<gAgg, 256, 0, stream>>>(Xb, rowptr, csrc, cursor, b2, Yb, N);
  // layer 3
  gemm_mfma_kernel<<<gGemm, 256, 0, stream>>>(Yb, Wt + (size_t)2 * D * D, cout_, Xb, N);
  agg_relu_kernel<<<gAgg, 256, 0, stream>>>(Xb, rowptr, csrc, cursor, b3, Yb, N);
  // layer 4
  gemm_mfma_kernel<<<gGemm, 256, 0, stream>>>(Yb, Wt + (size_t)3 * D * D, cout_, Xb, N);
  agg_relu_kernel<<<gAgg, 256, 0, stream>>>(Xb, rowptr, csrc, cursor, b4, Yb, N);

  pool_kernel<<<NG * 8, 128, 0, stream>>>(Yb, gid, sums, counts, N);
  classifier_kernel<<<1, 128, 0, stream>>>(sums, counts, Wc1, bc1, Wc2, bc2, out);
}